// Round 12
// baseline (1128.905 us; speedup 1.0000x reference)
//
#include <hip/hip_runtime.h>
#include <hip/hip_bf16.h>

typedef __attribute__((ext_vector_type(8))) short s8v;
typedef __attribute__((ext_vector_type(4))) float f32x4;
typedef __attribute__((ext_vector_type(2))) float f32x2;
typedef __attribute__((ext_vector_type(4))) unsigned u32x4;

#define MFMA16(A,B,C) __builtin_amdgcn_mfma_f32_16x16x32_bf16((A),(B),(C),0,0,0)

__device__ __forceinline__ float b2f(unsigned short s){
  union { unsigned u; float f; } v; v.u = ((unsigned)s) << 16; return v.f;
}
__device__ __forceinline__ unsigned short f2b(float f){
  union { float f; unsigned u; } v; v.f = f;
  return (unsigned short)((v.u + 0x8000u) >> 16);
}
__device__ __forceinline__ float siluf(float x){
  return x * __builtin_amdgcn_rcpf(1.f + __expf(-x));
}

// ---- packed helpers (gfx950 full-rate packed fp32) ----
// unpack 2 bf16 (one dword) -> 2 floats
__device__ __forceinline__ f32x2 unpk(unsigned u){
  union { unsigned u; float f; } lo, hi;
  lo.u = u << 16;
  hi.u = u & 0xFFFF0000u;
  return (f32x2){lo.f, hi.f};
}
// packed silu on a float pair (exp/rcp scalar, rest pk ops)
__device__ __forceinline__ f32x2 silu2(f32x2 x){
  f32x2 e;
  e.x = __expf(-x.x);
  e.y = __expf(-x.y);
  f32x2 d = e + 1.0f;
  f32x2 r;
  r.x = __builtin_amdgcn_rcpf(d.x);
  r.y = __builtin_amdgcn_rcpf(d.y);
  return x * r;
}
// packed f32x2 -> 2 bf16 in one dword (RNE, single v_cvt_pk on gfx950)
__device__ __forceinline__ unsigned pack_bf2(f32x2 v){
  union { __hip_bfloat162 h; unsigned u; } c;
  c.h = __float22bfloat162_rn(make_float2(v.x, v.y));
  return c.u;
}

// ---------- dtype sniffer (R4 evidence: inputs are fp32) ----------
__global__ void sniff_kernel(const unsigned short* __restrict__ raw,
                             int* __restrict__ flag, int n){
  int cnt = 0;
  for (int i = threadIdx.x; i < n; i += 64){
    unsigned v = raw[i] & 0x7FFFu;
    if (v >= 0x3F80u) cnt++;
  }
  #pragma unroll
  for (int off = 32; off; off >>= 1) cnt += __shfl_down(cnt, off, 64);
  if (threadIdx.x == 0) *flag = (cnt > 100) ? 1 : 0;
}

// ---------- canonicalize float tensors (params only; x handled separately) ----
struct CvtArgs {
  const void* src[19];
  float*      dst[19];
  int         n[19];
};
__global__ void cvt_all_kernel(CvtArgs a, const int* __restrict__ flag){
  const int f = *flag;
  const int gsz = gridDim.x * blockDim.x;
  const int gid = blockIdx.x * blockDim.x + threadIdx.x;
  for (int t = 0; t < 19; ++t){
    const int n = a.n[t];
    float* d = a.dst[t];
    if (f){
      const float* s = (const float*)a.src[t];
      for (int i = gid; i < n; i += gsz) d[i] = s[i];
    } else {
      const unsigned short* s = (const unsigned short*)a.src[t];
      for (int i = gid; i < n; i += gsz) d[i] = b2f(s[i]);
    }
  }
}

// x -> padded float4 (w unused): 1 dwordx4 gather in edge kernel instead of 3 loads
__global__ void cvt_x_pad_kernel(const void* __restrict__ xin,
                                 const int* __restrict__ flag,
                                 float4* __restrict__ xpad, int N){
  int i = blockIdx.x*256 + threadIdx.x;
  if (i >= N) return;
  float a, b, c;
  if (*flag){
    const float* s = (const float*)xin;
    a = s[i*3+0]; b = s[i*3+1]; c = s[i*3+2];
  } else {
    const unsigned short* s = (const unsigned short*)xin;
    a = b2f(s[i*3+0]); b = b2f(s[i*3+1]); c = b2f(s[i*3+2]);
  }
  xpad[i] = make_float4(a, b, c, 0.f);
}

// ---------- CSR build (edge list identical every call) ----------

__global__ void hist_kernel(const int* __restrict__ dst, int* __restrict__ deg, int E){
  int i = blockIdx.x*256 + threadIdx.x;
  if (i < E) atomicAdd(&deg[dst[i]], 1);
}

__global__ void scan1_kernel(const int* __restrict__ deg, int* __restrict__ rp,
                             int* __restrict__ bsum, int N){
  __shared__ int s[256];
  const int base = blockIdx.x*1024;
  const int t = threadIdx.x;
  int v[4];
  #pragma unroll
  for (int j = 0; j < 4; ++j){
    int idx = base + t*4 + j;
    v[j] = (idx < N) ? deg[idx] : 0;
  }
  const int tsum = v[0]+v[1]+v[2]+v[3];
  s[t] = tsum;
  __syncthreads();
  for (int off = 1; off < 256; off <<= 1){
    int x = (t >= off) ? s[t-off] : 0;
    __syncthreads();
    s[t] += x;
    __syncthreads();
  }
  const int incl = s[t];
  if (t == 255) bsum[blockIdx.x] = incl;
  int run = incl - tsum;
  #pragma unroll
  for (int j = 0; j < 4; ++j){
    int idx = base + t*4 + j;
    if (idx < N) rp[idx] = run;
    run += v[j];
  }
}

__global__ void scan2_kernel(int* __restrict__ bsum, int nb){
  __shared__ int s[256];
  const int t = threadIdx.x;
  const int v = (t < nb) ? bsum[t] : 0;
  s[t] = v;
  __syncthreads();
  for (int off = 1; off < 256; off <<= 1){
    int x = (t >= off) ? s[t-off] : 0;
    __syncthreads();
    s[t] += x;
    __syncthreads();
  }
  if (t < nb) bsum[t] = s[t] - v;
}

__global__ void scan3_kernel(int* __restrict__ rp, const int* __restrict__ bsum,
                             int N, int E){
  int i = blockIdx.x*256 + threadIdx.x;
  if (i < N) rp[i] += bsum[i >> 10];
  if (i == 0) rp[N] = E;
}

__global__ void scatter_kernel(const int* __restrict__ src, const int* __restrict__ dst,
                               const int* __restrict__ rp, int* __restrict__ cursor,
                               int* __restrict__ csr_src, int E){
  int i = blockIdx.x*256 + threadIdx.x;
  if (i < E){
    const int d = dst[i];
    const int pos = rp[d] + atomicAdd(&cursor[d], 1);
    csr_src[pos] = src[i];
  }
}

// ---------- small prologue kernels ----------

__global__ void tmean_kernel(const float* __restrict__ t,
                             const float* __restrict__ tw1,
                             const float* __restrict__ tb1,
                             const float* __restrict__ tw2,
                             const float* __restrict__ tb2,
                             float* __restrict__ tmean){
  __shared__ __align__(16) float s1[16*64];
  int j = threadIdx.x;
  float w1 = tw1[j], bb1 = tb1[j];
  for (int b = 0; b < 16; ++b)
    s1[b*64 + j] = siluf(t[b] * w1 + bb1);
  __syncthreads();
  float acc = 0.f;
  for (int b = 0; b < 16; ++b)
    for (int k = 0; k < 64; ++k)
      acc += s1[b*64 + k] * tw2[k*64 + j];
  tmean[j] = tb2[j] + acc * (1.f/16.f);
}

__global__ void init_h_kernel(const int* __restrict__ z,
                              const float* __restrict__ emb,
                              const float* __restrict__ tmean,
                              float* __restrict__ hf,
                              unsigned short* __restrict__ hb, int N){
  int i = blockIdx.x*256 + threadIdx.x;
  if (i >= N*64) return;
  int j = i & 63;
  int n = i >> 6;
  float v = emb[z[n]*64 + j] + tmean[j];
  hf[i] = v;
  hb[i] = f2b(v);
}

// ---------- p12: per-node MLP1 partials ----------

__global__ __launch_bounds__(512) void p12_kernel(
    const unsigned short* __restrict__ hb,
    const float* __restrict__ ew1, const float* __restrict__ eb1,
    unsigned short* __restrict__ P1, unsigned short* __restrict__ P2,
    int layer, int N)
{
  __shared__ __align__(16) short w1a[64*72];
  __shared__ __align__(16) short w1b[64*72];
  __shared__ __align__(16) float b1s[64];

  const int tid = threadIdx.x;
  const float* w1g = ew1 + layer*129*64;
  for (int idx = tid; idx < 64*64; idx += 512){
    int k = idx >> 6, n = idx & 63;
    w1a[n*72 + k] = (short)f2b(w1g[k*64 + n]);
    w1b[n*72 + k] = (short)f2b(w1g[(64 + k)*64 + n]);
  }
  if (tid < 64) b1s[tid] = eb1[layer*64 + tid];
  __syncthreads();

  const int lane = tid & 63;
  const int wv = tid >> 6;
  const int q = lane >> 4;
  const int n16 = lane & 15;

  const int ntile = N >> 4;
  const int step = gridDim.x * 8;
  for (int t = blockIdx.x*8 + wv; t < ntile; t += step){
    const int row = t*16 + n16;
    const s8v* ph = (const s8v*)(hb + row*64);
    const s8v a0 = ph[q];
    const s8v a1 = ph[4+q];
    #pragma unroll
    for (int nt = 0; nt < 4; ++nt){
      const s8v* wa = (const s8v*)&w1a[(nt*16 + n16)*72];
      const s8v* wb = (const s8v*)&w1b[(nt*16 + n16)*72];
      f32x4 aA = {0.f,0.f,0.f,0.f};
      aA = MFMA16(a0, wa[q],   aA);
      aA = MFMA16(a1, wa[4+q], aA);
      f32x4 aB = {0.f,0.f,0.f,0.f};
      aB = MFMA16(a0, wb[q],   aB);
      aB = MFMA16(a1, wb[4+q], aB);
      const float bb = b1s[nt*16 + n16];
      #pragma unroll
      for (int r = 0; r < 4; ++r){
        const int o = (t*16 + q*4 + r)*64 + nt*16 + n16;
        P1[o] = f2b(aA[r] + bb);
        P2[o] = f2b(aB[r]);
      }
    }
  }
}

// ---------- edge kernel (CSR): one wave per dst node, packed-math epilogues ----

__global__ __launch_bounds__(512) void edge_csr_kernel(
    const int* __restrict__ rp, const int* __restrict__ csr_src,
    const float4* __restrict__ xpad_in, float4* __restrict__ xpad_out,
    float* __restrict__ out3,
    const unsigned short* __restrict__ P1, const unsigned short* __restrict__ P2,
    unsigned short* __restrict__ aggb,
    const float* __restrict__ ew1,
    const float* __restrict__ ew2, const float* __restrict__ eb2,
    const float* __restrict__ cw1, const float* __restrict__ cb1,
    const float* __restrict__ cw2, const float* __restrict__ cb2,
    int layer, int do_agg, int N)
{
  __shared__ __align__(16) short wT2[64*72];    // e_w2^T [n][k]
  __shared__ __align__(16) short wc1T[64*72];   // c_w1^T
  __shared__ __align__(16) short sc[8][16*72];  // per-wave C->A transpose scratch
  __shared__ __align__(16) float sdiff[8][48];

  const int tid = threadIdx.x;
  const float* w2g = ew2 + layer*64*64;
  const float* c1g = cw1 + layer*64*64;
  for (int idx = tid; idx < 64*64; idx += 512){
    int k = idx >> 6, n = idx & 63;
    wT2[n*72 + k]  = (short)f2b(w2g[k*64 + n]);
    wc1T[n*72 + k] = (short)f2b(c1g[k*64 + n]);
  }

  const int lane = tid & 63;
  const int wv = tid >> 6;       // 0..7
  const int q = lane >> 4;       // quad 0..3
  const int n16 = lane & 15;
  short* mysc = sc[wv];
  float* mydiff = sdiff[wv];

  // per-lane loop-invariant constants in registers, packed where used packed
  const float* wlg = ew1 + layer*129*64 + 128*64;
  f32x2 wl_lo2[4], wl_hi2[4];
  #pragma unroll
  for (int p = 0; p < 4; ++p){
    wl_lo2[p] = (f32x2){wlg[q*8 + 2*p], wlg[q*8 + 2*p + 1]};
    wl_hi2[p] = (f32x2){wlg[32 + q*8 + 2*p], wlg[32 + q*8 + 2*p + 1]};
  }
  f32x2 be2v[4], bc1v[4], cw2v[4];
  #pragma unroll
  for (int nt = 0; nt < 4; ++nt){
    const float b2 = eb2[layer*64 + nt*16 + n16];
    const float bc = cb1[layer*64 + nt*16 + n16];
    const float wc = cw2[layer*64 + nt*16 + n16];
    be2v[nt] = (f32x2){b2, b2};
    bc1v[nt] = (f32x2){bc, bc};
    cw2v[nt] = (f32x2){wc, wc};
  }
  const float cb2s = cb2[layer];
  __syncthreads();

  const int nwave = gridDim.x * 8;
  for (int n = blockIdx.x*8 + wv; n < N; n += nwave){
    const int start = rp[n];
    const int deg = rp[n+1] - start;

    const u32x4* pd = (const u32x4*)(P1 + (size_t)n*64);
    const u32x4 lo1 = pd[q];
    const u32x4 hi1 = pd[4+q];
    const float4 xd4 = xpad_in[n];

    f32x2 colsumv[4] = {{0.f,0.f},{0.f,0.f},{0.f,0.f},{0.f,0.f}};
    f32x2 xaccv01 = {0.f,0.f};   // packed over coords (x,y)
    float xacc2 = 0.f;

    const int nch = (deg + 15) >> 4;
    for (int c = 0; c < nch; ++c){
      const int row = c*16 + n16;
      const int si = (row < deg) ? csr_src[start + row] : n;  // pad: self -> diff=0
      const float4 xs4 = xpad_in[si];
      const float dx = xd4.x - xs4.x;
      const float dy = xd4.y - xs4.y;
      const float dz = xd4.z - xs4.z;
      const float d2 = dx*dx + dy*dy + dz*dz;
      if (q == 0){ mydiff[n16*3+0]=dx; mydiff[n16*3+1]=dy; mydiff[n16*3+2]=dz; }
      const f32x2 d2v = (f32x2){d2, d2};

      const u32x4* ps = (const u32x4*)(P2 + (size_t)si*64);
      const u32x4 lo2 = ps[q];
      const u32x4 hi2 = ps[4+q];

      // ---- MLP1 combine, packed pairs -> A-frags ----
      union { s8v s; u32x4 u; } alo, ahi;
      #pragma unroll
      for (int p = 0; p < 4; ++p){
        f32x2 v0 = unpk(lo1[p]) + unpk(lo2[p]);
        v0 = v0 + d2v * wl_lo2[p];
        alo.u[p] = pack_bf2(silu2(v0));
        f32x2 v1 = unpk(hi1[p]) + unpk(hi2[p]);
        v1 = v1 + d2v * wl_hi2[p];
        ahi.u[p] = pack_bf2(silu2(v1));
      }

      // ---- MLP2: (16x64)@(64x64) ----
      f32x4 acc2[4];
      #pragma unroll
      for (int nt = 0; nt < 4; ++nt){
        const s8v* wb = (const s8v*)&wT2[(nt*16 + n16)*72];
        f32x4 a = {0.f,0.f,0.f,0.f};
        a = MFMA16(alo.s, wb[q],   a);
        a = MFMA16(ahi.s, wb[4+q], a);
        acc2[nt] = a;
      }
      // row-valid masks for colsum (rows c*16+q*4+r)
      const int rowbase = c*16 + q*4;
      const f32x2 mk01 = (f32x2){(rowbase+0 < deg) ? 1.f : 0.f,
                                 (rowbase+1 < deg) ? 1.f : 0.f};
      const f32x2 mk23 = (f32x2){(rowbase+2 < deg) ? 1.f : 0.f,
                                 (rowbase+3 < deg) ? 1.f : 0.f};
      const int col = 0; (void)col;
      #pragma unroll
      for (int nt = 0; nt < 4; ++nt){
        const f32x2 m01 = silu2((f32x2){acc2[nt][0], acc2[nt][1]} + be2v[nt]);
        const f32x2 m23 = silu2((f32x2){acc2[nt][2], acc2[nt][3]} + be2v[nt]);
        colsumv[nt] = colsumv[nt] + m01*mk01;
        colsumv[nt] = colsumv[nt] + m23*mk23;
        const unsigned pk01 = pack_bf2(m01);
        const unsigned pk23 = pack_bf2(m23);
        const int cidx = nt*16 + n16;
        mysc[(q*4+0)*72 + cidx] = (short)(pk01 & 0xFFFFu);
        mysc[(q*4+1)*72 + cidx] = (short)(pk01 >> 16);
        mysc[(q*4+2)*72 + cidx] = (short)(pk23 & 0xFFFFu);
        mysc[(q*4+3)*72 + cidx] = (short)(pk23 >> 16);
      }
      __builtin_amdgcn_wave_barrier();
      const s8v* srd = (const s8v*)&mysc[n16*72];
      const s8v m0 = srd[q];
      const s8v m1 = srd[4+q];
      __builtin_amdgcn_wave_barrier();

      // ---- coord MLP: silu(m@c_w1+b) @ c_w2 + b, packed epilogue ----
      f32x2 prv01 = {0.f,0.f}, prv23 = {0.f,0.f};
      #pragma unroll
      for (int nt = 0; nt < 4; ++nt){
        const s8v* wb = (const s8v*)&wc1T[(nt*16 + n16)*72];
        f32x4 a = {0.f,0.f,0.f,0.f};
        a = MFMA16(m0, wb[q],   a);
        a = MFMA16(m1, wb[4+q], a);
        prv01 = prv01 + silu2((f32x2){a[0], a[1]} + bc1v[nt]) * cw2v[nt];
        prv23 = prv23 + silu2((f32x2){a[2], a[3]} + bc1v[nt]) * cw2v[nt];
      }
      #pragma unroll
      for (int off = 1; off < 16; off <<= 1){
        f32x2 t0, t1;
        t0.x = __shfl_xor(prv01.x, off, 64); t0.y = __shfl_xor(prv01.y, off, 64);
        t1.x = __shfl_xor(prv23.x, off, 64); t1.y = __shfl_xor(prv23.y, off, 64);
        prv01 = prv01 + t0;
        prv23 = prv23 + t1;
      }
      const float prr[4] = {prv01.x, prv01.y, prv23.x, prv23.y};
      #pragma unroll
      for (int r = 0; r < 4; ++r){
        const float cwv = prr[r] + cb2s;
        const f32x2 dxy = (f32x2){mydiff[(q*4+r)*3 + 0], mydiff[(q*4+r)*3 + 1]};
        xaccv01 = xaccv01 + dxy * (f32x2){cwv, cwv};
        xacc2 += mydiff[(q*4+r)*3 + 2] * cwv;
      }
    }

    // reduce over quads (lanes differ only in bits 4,5) and lane pairs
    #pragma unroll
    for (int nt = 0; nt < 4; ++nt){
      f32x2 t;
      t.x = __shfl_xor(colsumv[nt].x, 16, 64); t.y = __shfl_xor(colsumv[nt].y, 16, 64);
      colsumv[nt] = colsumv[nt] + t;
      t.x = __shfl_xor(colsumv[nt].x, 32, 64); t.y = __shfl_xor(colsumv[nt].y, 32, 64);
      colsumv[nt] = colsumv[nt] + t;
    }
    {
      f32x2 t;
      t.x = __shfl_xor(xaccv01.x, 16, 64); t.y = __shfl_xor(xaccv01.y, 16, 64);
      xaccv01 = xaccv01 + t;
      t.x = __shfl_xor(xaccv01.x, 32, 64); t.y = __shfl_xor(xaccv01.y, 32, 64);
      xaccv01 = xaccv01 + t;
      xacc2 += __shfl_xor(xacc2, 16, 64); xacc2 += __shfl_xor(xacc2, 32, 64);
    }

    if (do_agg && q == 0){
      #pragma unroll
      for (int nt = 0; nt < 4; ++nt)
        aggb[(size_t)n*64 + nt*16 + n16] = f2b(colsumv[nt].x + colsumv[nt].y);
    }
    if (lane == 0){
      const float nx = xd4.x + xaccv01.x;
      const float ny = xd4.y + xaccv01.y;
      const float nz = xd4.z + xacc2;
      xpad_out[n] = make_float4(nx, ny, nz, 0.f);
      if (out3){
        out3[n*3+0] = nx; out3[n*3+1] = ny; out3[n*3+2] = nz;
      }
    }
  }
}

// ---------- node kernel: h += MLP([h | agg]), agg bf16 ----------

__global__ __launch_bounds__(512) void node_kernel(
    unsigned short* __restrict__ hb, float* __restrict__ hf,
    const unsigned short* __restrict__ aggb,
    const float* __restrict__ nw1, const float* __restrict__ nb1,
    const float* __restrict__ nw2, const float* __restrict__ nb2,
    int layer, int N)
{
  __shared__ __align__(16) short wT1[64*136];
  __shared__ __align__(16) short wT2[64*72];
  __shared__ __align__(16) short sc[8][16*72];
  __shared__ __align__(16) float b1s[64];
  __shared__ __align__(16) float b2s[64];

  const int tid = threadIdx.x;
  const float* w1g = nw1 + layer*128*64;
  const float* w2g = nw2 + layer*64*64;
  for (int idx = tid; idx < 64*128; idx += 512){
    int k = idx >> 6, n = idx & 63;
    wT1[n*136 + k] = (short)f2b(w1g[k*64 + n]);
  }
  for (int idx = tid; idx < 64*64; idx += 512){
    int k = idx >> 6, n = idx & 63;
    wT2[n*72 + k] = (short)f2b(w2g[k*64 + n]);
  }
  if (tid < 64){
    b1s[tid] = nb1[layer*64 + tid];
    b2s[tid] = nb2[layer*64 + tid];
  }
  __syncthreads();

  const int lane = tid & 63;
  const int wv = tid >> 6;
  const int q = lane >> 4;
  const int n16 = lane & 15;
  short* mysc = sc[wv];

  const int ntile = N >> 4;
  const int step = gridDim.x * 8;
  for (int t = blockIdx.x*8 + wv; t < ntile; t += step){
    const int row = t*16 + n16;
    const s8v* ph = (const s8v*)(hb + row*64);
    const s8v a0 = ph[q];
    const s8v a1 = ph[4+q];
    const s8v* pa = (const s8v*)(aggb + (size_t)row*64);
    const s8v a2 = pa[q];
    const s8v a3 = pa[4+q];
    #pragma unroll
    for (int nt = 0; nt < 4; ++nt){
      const s8v* wb = (const s8v*)&wT1[(nt*16 + n16)*136];
      f32x4 a = {0.f,0.f,0.f,0.f};
      a = MFMA16(a0, wb[q],    a);
      a = MFMA16(a1, wb[4+q],  a);
      a = MFMA16(a2, wb[8+q],  a);
      a = MFMA16(a3, wb[12+q], a);
      const float bb = b1s[nt*16 + n16];
      const f32x2 bbv = (f32x2){bb, bb};
      const f32x2 m01 = silu2((f32x2){a[0], a[1]} + bbv);
      const f32x2 m23 = silu2((f32x2){a[2], a[3]} + bbv);
      const unsigned pk01 = pack_bf2(m01);
      const unsigned pk23 = pack_bf2(m23);
      const int cidx = nt*16 + n16;
      mysc[(q*4+0)*72 + cidx] = (short)(pk01 & 0xFFFFu);
      mysc[(q*4+1)*72 + cidx] = (short)(pk01 >> 16);
      mysc[(q*4+2)*72 + cidx] = (short)(pk23 & 0xFFFFu);
      mysc[(q*4+3)*72 + cidx] = (short)(pk23 >> 16);
    }
    __builtin_amdgcn_wave_barrier();
    const s8v* srd = (const s8v*)&mysc[n16*72];
    const s8v g0 = srd[q];
    const s8v g1 = srd[4+q];
    __builtin_amdgcn_wave_barrier();
    #pragma unroll
    for (int nt = 0; nt < 4; ++nt){
      const s8v* wb = (const s8v*)&wT2[(nt*16 + n16)*72];
      f32x4 a = {0.f,0.f,0.f,0.f};
      a = MFMA16(g0, wb[q],   a);
      a = MFMA16(g1, wb[4+q], a);
      const float bb = b2s[nt*16 + n16];
      #pragma unroll
      for (int r = 0; r < 4; ++r){
        const int idx = (t*16 + q*4 + r)*64 + nt*16 + n16;
        const float hv = hf[idx] + a[r] + bb;
        hf[idx] = hv;
        hb[idx] = f2b(hv);
      }
    }
  }
}

// ---------- launch ----------

extern "C" void kernel_launch(void* const* d_in, const int* in_sizes, int n_in,
                              void* d_out, int out_size, void* d_ws, size_t ws_size,
                              hipStream_t stream)
{
  const int* z   = (const int*)d_in[1];
  const int* ei  = (const int*)d_in[3];

  const int N = in_sizes[1];
  const int E = in_sizes[3] / 2;
  const int* srcp = ei;
  const int* dstp = ei + E;

  char* p = (char*)d_ws;
  auto alloc = [&](size_t bytes) -> void* {
    void* r = (void*)p; p += (bytes + 255) & ~(size_t)255; return r;
  };
  float* hf            = (float*)alloc((size_t)N*64*4);
  unsigned short* hbuf = (unsigned short*)alloc((size_t)N*64*2);
  unsigned short* aggb = (unsigned short*)alloc((size_t)N*64*2);
  unsigned short* P1   = (unsigned short*)alloc((size_t)N*64*2);
  unsigned short* P2   = (unsigned short*)alloc((size_t)N*64*2);
  float4* xpa          = (float4*)alloc((size_t)N*16);
  float4* xpb          = (float4*)alloc((size_t)N*16);
  float* tmean         = (float*)alloc(64*4);
  int*   flag          = (int*)alloc(256);
  int*   deg           = (int*)alloc((size_t)N*4);
  int*   cursor        = (int*)alloc((size_t)N*4);
  int*   rowp          = (int*)alloc((size_t)(N+1)*4);
  int*   bsum          = (int*)alloc(256*4);
  int*   csr_src       = (int*)alloc((size_t)E*4);

  // Float param tensors (x excluded — handled by cvt_x_pad):
  // 2:t 4:emb 5..8:tmlp 9..12:e 13..16:c 17..20:n  (18 total)
  int FT[18];
  {
    int c = 0;
    FT[c++] = 2;
    for (int ii = 4; ii <= 20; ++ii) FT[c++] = ii;
  }

  CvtArgs ca;
  float* canon[21] = {nullptr};
  for (int j = 0; j < 18; ++j){
    const int ii = FT[j];
    ca.src[j] = d_in[ii];
    ca.n[j]   = in_sizes[ii];
    ca.dst[j] = (float*)alloc((size_t)in_sizes[ii]*4);
    canon[ii] = ca.dst[j];
  }
  ca.src[18] = d_in[2]; ca.dst[18] = (float*)tmean; ca.n[18] = 0;  // unused slot

  const float *tc = canon[2], *embc = canon[4];
  const float *tw1c = canon[5], *tb1c = canon[6], *tw2c = canon[7], *tb2c = canon[8];
  const float *ew1c = canon[9], *eb1c = canon[10], *ew2c = canon[11], *eb2c = canon[12];
  const float *cw1c = canon[13], *cb1c = canon[14], *cw2c = canon[15], *cb2c = canon[16];
  const float *nw1c = canon[17], *nb1c = canon[18], *nw2c = canon[19], *nb2c = canon[20];

  sniff_kernel<<<1, 64, 0, stream>>>((const unsigned short*)d_in[4], flag, in_sizes[4]);
  cvt_all_kernel<<<256, 256, 0, stream>>>(ca, flag);
  cvt_x_pad_kernel<<<(N + 255)/256, 256, 0, stream>>>(d_in[0], flag, xpa, N);
  tmean_kernel<<<1, 64, 0, stream>>>(tc, tw1c, tb1c, tw2c, tb2c, tmean);
  init_h_kernel<<<(N*64 + 255)/256, 256, 0, stream>>>(z, embc, tmean, hf, hbuf, N);

  // ---- CSR build (once; edges fixed across layers) ----
  (void)hipMemsetAsync(deg, 0, (size_t)N*4, stream);
  (void)hipMemsetAsync(cursor, 0, (size_t)N*4, stream);
  hist_kernel<<<(E + 255)/256, 256, 0, stream>>>(dstp, deg, E);
  const int nb = (N + 1023)/1024;
  scan1_kernel<<<nb, 256, 0, stream>>>(deg, rowp, bsum, N);
  scan2_kernel<<<1, 256, 0, stream>>>(bsum, nb);
  scan3_kernel<<<(N + 255)/256, 256, 0, stream>>>(rowp, bsum, N, E);
  scatter_kernel<<<(E + 255)/256, 256, 0, stream>>>(srcp, dstp, rowp, cursor, csr_src, E);

  float4* xc = xpa;
  float4* xn = xpb;
  for (int l = 0; l < 3; ++l){
    float* out3 = (l == 2) ? (float*)d_out : nullptr;
    p12_kernel<<<256, 512, 0, stream>>>(hbuf, ew1c, eb1c, P1, P2, l, N);
    edge_csr_kernel<<<1024, 512, 0, stream>>>(rowp, csr_src, xc, xn, out3, P1, P2, aggb,
        ew1c, ew2c, eb2c, cw1c, cb1c, cw2c, cb2c, l, (l < 2) ? 1 : 0, N);
    if (l < 2)
      node_kernel<<<256, 512, 0, stream>>>(hbuf, hf, aggb, nw1c, nb1c, nw2c, nb2c, l, N);
    float4* tmp = xc; xc = xn; xn = tmp;
  }
}

// Round 13
// 988.656 us; speedup vs baseline: 1.1419x; 1.1419x over previous
//
#include <hip/hip_runtime.h>

typedef __attribute__((ext_vector_type(8))) short s8v;
typedef __attribute__((ext_vector_type(4))) float f32x4;

#define MFMA16(A,B,C) __builtin_amdgcn_mfma_f32_16x16x32_bf16((A),(B),(C),0,0,0)

__device__ __forceinline__ float b2f(unsigned short s){
  union { unsigned u; float f; } v; v.u = ((unsigned)s) << 16; return v.f;
}
// 2-op bf16 convert (round-half-up)
__device__ __forceinline__ unsigned short f2b(float f){
  union { float f; unsigned u; } v; v.f = f;
  return (unsigned short)((v.u + 0x8000u) >> 16);
}
// silu via v_rcp_f32 (1 ulp) instead of IEEE division sequence
__device__ __forceinline__ float siluf(float x){
  return x * __builtin_amdgcn_rcpf(1.f + __expf(-x));
}

// ---------- CSR build (edge list identical every call) ----------

__global__ void hist_kernel(const int* __restrict__ dst, int* __restrict__ deg, int E){
  int i = blockIdx.x*256 + threadIdx.x;
  if (i < E) atomicAdd(&deg[dst[i]], 1);
}

__global__ void scan1_kernel(const int* __restrict__ deg, int* __restrict__ rp,
                             int* __restrict__ bsum, int N){
  __shared__ int s[256];
  const int base = blockIdx.x*1024;
  const int t = threadIdx.x;
  int v[4];
  #pragma unroll
  for (int j = 0; j < 4; ++j){
    int idx = base + t*4 + j;
    v[j] = (idx < N) ? deg[idx] : 0;
  }
  const int tsum = v[0]+v[1]+v[2]+v[3];
  s[t] = tsum;
  __syncthreads();
  for (int off = 1; off < 256; off <<= 1){
    int x = (t >= off) ? s[t-off] : 0;
    __syncthreads();
    s[t] += x;
    __syncthreads();
  }
  const int incl = s[t];
  if (t == 255) bsum[blockIdx.x] = incl;
  int run = incl - tsum;
  #pragma unroll
  for (int j = 0; j < 4; ++j){
    int idx = base + t*4 + j;
    if (idx < N) rp[idx] = run;
    run += v[j];
  }
}

__global__ void scan2_kernel(int* __restrict__ bsum, int nb){
  __shared__ int s[256];
  const int t = threadIdx.x;
  const int v = (t < nb) ? bsum[t] : 0;
  s[t] = v;
  __syncthreads();
  for (int off = 1; off < 256; off <<= 1){
    int x = (t >= off) ? s[t-off] : 0;
    __syncthreads();
    s[t] += x;
    __syncthreads();
  }
  if (t < nb) bsum[t] = s[t] - v;
}

__global__ void scan3_kernel(int* __restrict__ rp, const int* __restrict__ bsum,
                             int N, int E){
  int i = blockIdx.x*256 + threadIdx.x;
  if (i < N) rp[i] += bsum[i >> 10];
  if (i == 0) rp[N] = E;
}

__global__ void scatter_kernel(const int* __restrict__ src, const int* __restrict__ dst,
                               const int* __restrict__ rp, int* __restrict__ cursor,
                               int* __restrict__ csr_src, int E){
  int i = blockIdx.x*256 + threadIdx.x;
  if (i < E){
    const int d = dst[i];
    const int pos = rp[d] + atomicAdd(&cursor[d], 1);
    csr_src[pos] = src[i];
  }
}

// ---------- small prologue kernels (inputs are fp32 — R4..R11 evidence) ----------

__global__ void tmean_kernel(const float* __restrict__ t,
                             const float* __restrict__ tw1,
                             const float* __restrict__ tb1,
                             const float* __restrict__ tw2,
                             const float* __restrict__ tb2,
                             float* __restrict__ tmean){
  __shared__ __align__(16) float s1[16*64];
  int j = threadIdx.x;
  float w1 = tw1[j], bb1 = tb1[j];
  for (int b = 0; b < 16; ++b)
    s1[b*64 + j] = siluf(t[b] * w1 + bb1);
  __syncthreads();
  float acc = 0.f;
  for (int b = 0; b < 16; ++b)
    for (int k = 0; k < 64; ++k)
      acc += s1[b*64 + k] * tw2[k*64 + j];
  tmean[j] = tb2[j] + acc * (1.f/16.f);
}

__global__ void init_h_kernel(const int* __restrict__ z,
                              const float* __restrict__ emb,
                              const float* __restrict__ tmean,
                              float* __restrict__ hf,
                              unsigned short* __restrict__ hb, int N){
  int i = blockIdx.x*256 + threadIdx.x;
  if (i >= N*64) return;
  int j = i & 63;
  int n = i >> 6;
  float v = emb[z[n]*64 + j] + tmean[j];
  hf[i] = v;
  hb[i] = f2b(v);
}

// ---------- p12: per-node MLP1 partials ----------

__global__ __launch_bounds__(512) void p12_kernel(
    const unsigned short* __restrict__ hb,
    const float* __restrict__ ew1, const float* __restrict__ eb1,
    unsigned short* __restrict__ P1, unsigned short* __restrict__ P2,
    int layer, int N)
{
  __shared__ __align__(16) short w1a[64*72];
  __shared__ __align__(16) short w1b[64*72];
  __shared__ __align__(16) float b1s[64];

  const int tid = threadIdx.x;
  const float* w1g = ew1 + layer*129*64;
  for (int idx = tid; idx < 64*64; idx += 512){
    int k = idx >> 6, n = idx & 63;
    w1a[n*72 + k] = (short)f2b(w1g[k*64 + n]);
    w1b[n*72 + k] = (short)f2b(w1g[(64 + k)*64 + n]);
  }
  if (tid < 64) b1s[tid] = eb1[layer*64 + tid];
  __syncthreads();

  const int lane = tid & 63;
  const int wv = tid >> 6;
  const int q = lane >> 4;
  const int n16 = lane & 15;

  const int ntile = N >> 4;
  const int step = gridDim.x * 8;
  for (int t = blockIdx.x*8 + wv; t < ntile; t += step){
    const int row = t*16 + n16;
    const s8v* ph = (const s8v*)(hb + row*64);
    const s8v a0 = ph[q];
    const s8v a1 = ph[4+q];
    #pragma unroll
    for (int nt = 0; nt < 4; ++nt){
      const s8v* wa = (const s8v*)&w1a[(nt*16 + n16)*72];
      const s8v* wb = (const s8v*)&w1b[(nt*16 + n16)*72];
      f32x4 aA = {0.f,0.f,0.f,0.f};
      aA = MFMA16(a0, wa[q],   aA);
      aA = MFMA16(a1, wa[4+q], aA);
      f32x4 aB = {0.f,0.f,0.f,0.f};
      aB = MFMA16(a0, wb[q],   aB);
      aB = MFMA16(a1, wb[4+q], aB);
      const float bb = b1s[nt*16 + n16];
      #pragma unroll
      for (int r = 0; r < 4; ++r){
        const int o = (t*16 + q*4 + r)*64 + nt*16 + n16;
        P1[o] = f2b(aA[r] + bb);
        P2[o] = f2b(aB[r]);
      }
    }
  }
}

// ---------- edge kernel (CSR): one wave per dst node, NO atomics ----------
// (byte-identical to R10's proven 230 µs / VGPR 64 version)

__global__ __launch_bounds__(512) void edge_csr_kernel(
    const int* __restrict__ rp, const int* __restrict__ csr_src,
    const float* __restrict__ x_in, float* __restrict__ x_out,
    const unsigned short* __restrict__ P1, const unsigned short* __restrict__ P2,
    unsigned short* __restrict__ aggb,
    const float* __restrict__ ew1,
    const float* __restrict__ ew2, const float* __restrict__ eb2,
    const float* __restrict__ cw1, const float* __restrict__ cb1,
    const float* __restrict__ cw2, const float* __restrict__ cb2,
    int layer, int do_agg, int N)
{
  __shared__ __align__(16) short wT2[64*72];    // e_w2^T [n][k]
  __shared__ __align__(16) short wc1T[64*72];   // c_w1^T
  __shared__ __align__(16) short sc[8][16*72];  // per-wave C->A transpose scratch
  __shared__ __align__(16) float sdiff[8][48];

  const int tid = threadIdx.x;
  const float* w2g = ew2 + layer*64*64;
  const float* c1g = cw1 + layer*64*64;
  for (int idx = tid; idx < 64*64; idx += 512){
    int k = idx >> 6, n = idx & 63;
    wT2[n*72 + k]  = (short)f2b(w2g[k*64 + n]);
    wc1T[n*72 + k] = (short)f2b(c1g[k*64 + n]);
  }

  const int lane = tid & 63;
  const int wv = tid >> 6;       // 0..7
  const int q = lane >> 4;       // quad 0..3
  const int n16 = lane & 15;
  short* mysc = sc[wv];
  float* mydiff = sdiff[wv];

  // per-lane loop-invariant constants in registers
  const float* wlg = ew1 + layer*129*64 + 128*64;
  float wl_lo[8], wl_hi[8];
  #pragma unroll
  for (int j = 0; j < 8; ++j){
    wl_lo[j] = wlg[q*8 + j];
    wl_hi[j] = wlg[32 + q*8 + j];
  }
  float be2r[4], bc1r[4], cw2r[4];
  #pragma unroll
  for (int nt = 0; nt < 4; ++nt){
    be2r[nt] = eb2[layer*64 + nt*16 + n16];
    bc1r[nt] = cb1[layer*64 + nt*16 + n16];
    cw2r[nt] = cw2[layer*64 + nt*16 + n16];
  }
  const float cb2s = cb2[layer];
  __syncthreads();

  const int nwave = gridDim.x * 8;
  for (int n = blockIdx.x*8 + wv; n < N; n += nwave){
    const int start = rp[n];
    const int deg = rp[n+1] - start;

    const s8v* pd = (const s8v*)(P1 + (size_t)n*64);
    const s8v lo1 = pd[q];
    const s8v hi1 = pd[4+q];
    const float xd0 = x_in[n*3+0];
    const float xd1 = x_in[n*3+1];
    const float xd2 = x_in[n*3+2];

    float colsum[4] = {0.f,0.f,0.f,0.f};
    float xacc0 = 0.f, xacc1 = 0.f, xacc2 = 0.f;

    const int nch = (deg + 15) >> 4;
    for (int c = 0; c < nch; ++c){
      const int row = c*16 + n16;
      const int si = (row < deg) ? csr_src[start + row] : n;  // pad: self -> diff=0
      const float xs0 = x_in[si*3+0];
      const float xs1 = x_in[si*3+1];
      const float xs2 = x_in[si*3+2];
      const float dx = xd0 - xs0;
      const float dy = xd1 - xs1;
      const float dz = xd2 - xs2;
      const float d2 = dx*dx + dy*dy + dz*dz;
      if (q == 0){ mydiff[n16*3+0]=dx; mydiff[n16*3+1]=dy; mydiff[n16*3+2]=dz; }

      const s8v* ps = (const s8v*)(P2 + (size_t)si*64);
      const s8v lo2 = ps[q];
      const s8v hi2 = ps[4+q];

      // MLP1 combine in registers (A-layout)
      s8v alo, ahi;
      #pragma unroll
      for (int j = 0; j < 8; ++j){
        const float v0 = b2f((unsigned short)lo1[j]) + b2f((unsigned short)lo2[j]) + d2*wl_lo[j];
        alo[j] = (short)f2b(siluf(v0));
        const float v1 = b2f((unsigned short)hi1[j]) + b2f((unsigned short)hi2[j]) + d2*wl_hi[j];
        ahi[j] = (short)f2b(siluf(v1));
      }

      // MLP2: (16x64)@(64x64)
      f32x4 acc2[4];
      #pragma unroll
      for (int nt = 0; nt < 4; ++nt){
        const s8v* wb = (const s8v*)&wT2[(nt*16 + n16)*72];
        f32x4 a = {0.f,0.f,0.f,0.f};
        a = MFMA16(alo, wb[q],   a);
        a = MFMA16(ahi, wb[4+q], a);
        acc2[nt] = a;
      }
      const int rowbase = c*16 + q*4;
      #pragma unroll
      for (int nt = 0; nt < 4; ++nt){
        const float bb = be2r[nt];
        #pragma unroll
        for (int r = 0; r < 4; ++r){
          const float mv = siluf(acc2[nt][r] + bb);
          mysc[(q*4 + r)*72 + nt*16 + n16] = (short)f2b(mv);
          colsum[nt] += (rowbase + r < deg) ? mv : 0.f;
        }
      }
      __builtin_amdgcn_wave_barrier();
      const s8v* srd = (const s8v*)&mysc[n16*72];
      const s8v m0 = srd[q];
      const s8v m1 = srd[4+q];
      __builtin_amdgcn_wave_barrier();

      // coord MLP: silu(m@c_w1+b) @ c_w2 + b
      float pr[4] = {0.f,0.f,0.f,0.f};
      #pragma unroll
      for (int nt = 0; nt < 4; ++nt){
        const s8v* wb = (const s8v*)&wc1T[(nt*16 + n16)*72];
        f32x4 a = {0.f,0.f,0.f,0.f};
        a = MFMA16(m0, wb[q],   a);
        a = MFMA16(m1, wb[4+q], a);
        const float bc = bc1r[nt];
        const float wc2 = cw2r[nt];
        #pragma unroll
        for (int r = 0; r < 4; ++r) pr[r] += siluf(a[r] + bc) * wc2;
      }
      #pragma unroll
      for (int off = 1; off < 16; off <<= 1){
        #pragma unroll
        for (int r = 0; r < 4; ++r) pr[r] += __shfl_xor(pr[r], off, 64);
      }
      #pragma unroll
      for (int r = 0; r < 4; ++r){
        const float cwv = pr[r] + cb2s;
        xacc0 += mydiff[(q*4 + r)*3 + 0] * cwv;
        xacc1 += mydiff[(q*4 + r)*3 + 1] * cwv;
        xacc2 += mydiff[(q*4 + r)*3 + 2] * cwv;
      }
    }

    #pragma unroll
    for (int nt = 0; nt < 4; ++nt){
      colsum[nt] += __shfl_xor(colsum[nt], 16, 64);
      colsum[nt] += __shfl_xor(colsum[nt], 32, 64);
    }
    xacc0 += __shfl_xor(xacc0, 16, 64); xacc0 += __shfl_xor(xacc0, 32, 64);
    xacc1 += __shfl_xor(xacc1, 16, 64); xacc1 += __shfl_xor(xacc1, 32, 64);
    xacc2 += __shfl_xor(xacc2, 16, 64); xacc2 += __shfl_xor(xacc2, 32, 64);

    if (do_agg && q == 0){
      #pragma unroll
      for (int nt = 0; nt < 4; ++nt)
        aggb[(size_t)n*64 + nt*16 + n16] = f2b(colsum[nt]);
    }
    if (lane == 0){
      x_out[n*3+0] = xd0 + xacc0;
      x_out[n*3+1] = xd1 + xacc1;
      x_out[n*3+2] = xd2 + xacc2;
    }
  }
}

// ---------- node kernel: h += MLP([h | agg]), agg bf16 ----------

__global__ __launch_bounds__(512) void node_kernel(
    unsigned short* __restrict__ hb, float* __restrict__ hf,
    const unsigned short* __restrict__ aggb,
    const float* __restrict__ nw1, const float* __restrict__ nb1,
    const float* __restrict__ nw2, const float* __restrict__ nb2,
    int layer, int N)
{
  __shared__ __align__(16) short wT1[64*136];
  __shared__ __align__(16) short wT2[64*72];
  __shared__ __align__(16) short sc[8][16*72];
  __shared__ __align__(16) float b1s[64];
  __shared__ __align__(16) float b2s[64];

  const int tid = threadIdx.x;
  const float* w1g = nw1 + layer*128*64;
  const float* w2g = nw2 + layer*64*64;
  for (int idx = tid; idx < 64*128; idx += 512){
    int k = idx >> 6, n = idx & 63;
    wT1[n*136 + k] = (short)f2b(w1g[k*64 + n]);
  }
  for (int idx = tid; idx < 64*64; idx += 512){
    int k = idx >> 6, n = idx & 63;
    wT2[n*72 + k] = (short)f2b(w2g[k*64 + n]);
  }
  if (tid < 64){
    b1s[tid] = nb1[layer*64 + tid];
    b2s[tid] = nb2[layer*64 + tid];
  }
  __syncthreads();

  const int lane = tid & 63;
  const int wv = tid >> 6;
  const int q = lane >> 4;
  const int n16 = lane & 15;
  short* mysc = sc[wv];

  const int ntile = N >> 4;
  const int step = gridDim.x * 8;
  for (int t = blockIdx.x*8 + wv; t < ntile; t += step){
    const int row = t*16 + n16;
    const s8v* ph = (const s8v*)(hb + row*64);
    const s8v a0 = ph[q];
    const s8v a1 = ph[4+q];
    const s8v* pa = (const s8v*)(aggb + (size_t)row*64);
    const s8v a2 = pa[q];
    const s8v a3 = pa[4+q];
    #pragma unroll
    for (int nt = 0; nt < 4; ++nt){
      const s8v* wb = (const s8v*)&wT1[(nt*16 + n16)*136];
      f32x4 a = {0.f,0.f,0.f,0.f};
      a = MFMA16(a0, wb[q],    a);
      a = MFMA16(a1, wb[4+q],  a);
      a = MFMA16(a2, wb[8+q],  a);
      a = MFMA16(a3, wb[12+q], a);
      const float bb = b1s[nt*16 + n16];
      #pragma unroll
      for (int r = 0; r < 4; ++r)
        mysc[(q*4 + r)*72 + nt*16 + n16] = (short)f2b(siluf(a[r] + bb));
    }
    __builtin_amdgcn_wave_barrier();
    const s8v* srd = (const s8v*)&mysc[n16*72];
    const s8v g0 = srd[q];
    const s8v g1 = srd[4+q];
    __builtin_amdgcn_wave_barrier();
    #pragma unroll
    for (int nt = 0; nt < 4; ++nt){
      const s8v* wb = (const s8v*)&wT2[(nt*16 + n16)*72];
      f32x4 a = {0.f,0.f,0.f,0.f};
      a = MFMA16(g0, wb[q],   a);
      a = MFMA16(g1, wb[4+q], a);
      const float bb = b2s[nt*16 + n16];
      #pragma unroll
      for (int r = 0; r < 4; ++r){
        const int idx = (t*16 + q*4 + r)*64 + nt*16 + n16;
        const float hv = hf[idx] + a[r] + bb;
        hf[idx] = hv;
        hb[idx] = f2b(hv);
      }
    }
  }
}

// ---------- launch ----------

extern "C" void kernel_launch(void* const* d_in, const int* in_sizes, int n_in,
                              void* d_out, int out_size, void* d_ws, size_t ws_size,
                              hipStream_t stream)
{
  // Inputs are fp32 (established R4..R11). Read d_in directly — no canonicalization.
  const float* x0   = (const float*)d_in[0];
  const int*   z    = (const int*)d_in[1];
  const float* tc   = (const float*)d_in[2];
  const int*   ei   = (const int*)d_in[3];
  const float* embc = (const float*)d_in[4];
  const float* tw1c = (const float*)d_in[5];
  const float* tb1c = (const float*)d_in[6];
  const float* tw2c = (const float*)d_in[7];
  const float* tb2c = (const float*)d_in[8];
  const float* ew1c = (const float*)d_in[9];
  const float* eb1c = (const float*)d_in[10];
  const float* ew2c = (const float*)d_in[11];
  const float* eb2c = (const float*)d_in[12];
  const float* cw1c = (const float*)d_in[13];
  const float* cb1c = (const float*)d_in[14];
  const float* cw2c = (const float*)d_in[15];
  const float* cb2c = (const float*)d_in[16];
  const float* nw1c = (const float*)d_in[17];
  const float* nb1c = (const float*)d_in[18];
  const float* nw2c = (const float*)d_in[19];
  const float* nb2c = (const float*)d_in[20];

  const int N = in_sizes[1];
  const int E = in_sizes[3] / 2;
  const int* srcp = ei;
  const int* dstp = ei + E;

  char* p = (char*)d_ws;
  auto alloc = [&](size_t bytes) -> void* {
    void* r = (void*)p; p += (bytes + 255) & ~(size_t)255; return r;
  };
  float* hf            = (float*)alloc((size_t)N*64*4);
  unsigned short* hbuf = (unsigned short*)alloc((size_t)N*64*2);
  unsigned short* aggb = (unsigned short*)alloc((size_t)N*64*2);
  unsigned short* P1   = (unsigned short*)alloc((size_t)N*64*2);
  unsigned short* P2   = (unsigned short*)alloc((size_t)N*64*2);
  float* xa            = (float*)alloc((size_t)N*3*4);
  float* xb            = (float*)alloc((size_t)N*3*4);
  float* tmean         = (float*)alloc(64*4);
  int*   degcur        = (int*)alloc((size_t)2*N*4);   // deg | cursor (one memset)
  int*   deg           = degcur;
  int*   cursor        = degcur + N;
  int*   rowp          = (int*)alloc((size_t)(N+1)*4);
  int*   bsum          = (int*)alloc(256*4);
  int*   csr_src       = (int*)alloc((size_t)E*4);

  tmean_kernel<<<1, 64, 0, stream>>>(tc, tw1c, tb1c, tw2c, tb2c, tmean);
  init_h_kernel<<<(N*64 + 255)/256, 256, 0, stream>>>(z, embc, tmean, hf, hbuf, N);

  // ---- CSR build (once; edges fixed across layers) ----
  (void)hipMemsetAsync(degcur, 0, (size_t)2*N*4, stream);
  hist_kernel<<<(E + 255)/256, 256, 0, stream>>>(dstp, deg, E);
  const int nb = (N + 1023)/1024;
  scan1_kernel<<<nb, 256, 0, stream>>>(deg, rowp, bsum, N);
  scan2_kernel<<<1, 256, 0, stream>>>(bsum, nb);
  scan3_kernel<<<(N + 255)/256, 256, 0, stream>>>(rowp, bsum, N, E);
  scatter_kernel<<<(E + 255)/256, 256, 0, stream>>>(srcp, dstp, rowp, cursor, csr_src, E);

  const float* xc = x0;   // layer 0 reads input x directly
  float* xnexts[3] = {xa, xb, (float*)d_out};
  for (int l = 0; l < 3; ++l){
    float* xout = xnexts[l];
    p12_kernel<<<256, 512, 0, stream>>>(hbuf, ew1c, eb1c, P1, P2, l, N);
    edge_csr_kernel<<<1024, 512, 0, stream>>>(rowp, csr_src, xc, xout, P1, P2, aggb,
        ew1c, ew2c, eb2c, cw1c, cb1c, cw2c, cb2c, l, (l < 2) ? 1 : 0, N);
    if (l < 2)
      node_kernel<<<256, 512, 0, stream>>>(hbuf, hf, aggb, nw1c, nb1c, nw2c, nb2c, l, N);
    xc = xout;
  }
}

// Round 14
// 945.500 us; speedup vs baseline: 1.1940x; 1.0456x over previous
//
#include <hip/hip_runtime.h>

typedef __attribute__((ext_vector_type(8))) short s8v;
typedef __attribute__((ext_vector_type(4))) float f32x4;

#define MFMA16(A,B,C) __builtin_amdgcn_mfma_f32_16x16x32_bf16((A),(B),(C),0,0,0)

__device__ __forceinline__ float b2f(unsigned short s){
  union { unsigned u; float f; } v; v.u = ((unsigned)s) << 16; return v.f;
}
// 2-op bf16 convert (round-half-up)
__device__ __forceinline__ unsigned short f2b(float f){
  union { float f; unsigned u; } v; v.f = f;
  return (unsigned short)((v.u + 0x8000u) >> 16);
}
// silu via v_rcp_f32 (1 ulp) instead of IEEE division sequence
__device__ __forceinline__ float siluf(float x){
  return x * __builtin_amdgcn_rcpf(1.f + __expf(-x));
}

// ---------- CSR build (edge list identical every call) ----------

__global__ void hist_kernel(const int* __restrict__ dst, int* __restrict__ deg, int E){
  int i = blockIdx.x*256 + threadIdx.x;
  if (i < E) atomicAdd(&deg[dst[i]], 1);
}

__global__ void scan1_kernel(const int* __restrict__ deg, int* __restrict__ rp,
                             int* __restrict__ bsum, int N){
  __shared__ int s[256];
  const int base = blockIdx.x*1024;
  const int t = threadIdx.x;
  int v[4];
  #pragma unroll
  for (int j = 0; j < 4; ++j){
    int idx = base + t*4 + j;
    v[j] = (idx < N) ? deg[idx] : 0;
  }
  const int tsum = v[0]+v[1]+v[2]+v[3];
  s[t] = tsum;
  __syncthreads();
  for (int off = 1; off < 256; off <<= 1){
    int x = (t >= off) ? s[t-off] : 0;
    __syncthreads();
    s[t] += x;
    __syncthreads();
  }
  const int incl = s[t];
  if (t == 255) bsum[blockIdx.x] = incl;
  int run = incl - tsum;
  #pragma unroll
  for (int j = 0; j < 4; ++j){
    int idx = base + t*4 + j;
    if (idx < N) rp[idx] = run;
    run += v[j];
  }
}

__global__ void scan2_kernel(int* __restrict__ bsum, int nb){
  __shared__ int s[256];
  const int t = threadIdx.x;
  const int v = (t < nb) ? bsum[t] : 0;
  s[t] = v;
  __syncthreads();
  for (int off = 1; off < 256; off <<= 1){
    int x = (t >= off) ? s[t-off] : 0;
    __syncthreads();
    s[t] += x;
    __syncthreads();
  }
  if (t < nb) bsum[t] = s[t] - v;
}

__global__ void scan3_kernel(int* __restrict__ rp, const int* __restrict__ bsum,
                             int N, int E){
  int i = blockIdx.x*256 + threadIdx.x;
  if (i < N) rp[i] += bsum[i >> 10];
  if (i == 0) rp[N] = E;
}

__global__ void scatter_kernel(const int* __restrict__ src, const int* __restrict__ dst,
                               const int* __restrict__ rp, int* __restrict__ cursor,
                               int* __restrict__ csr_src, int E){
  int i = blockIdx.x*256 + threadIdx.x;
  if (i < E){
    const int d = dst[i];
    const int pos = rp[d] + atomicAdd(&cursor[d], 1);
    csr_src[pos] = src[i];
  }
}

// ---------- small prologue kernels (inputs are fp32 — R4..R12 evidence) ----------

__global__ void tmean_kernel(const float* __restrict__ t,
                             const float* __restrict__ tw1,
                             const float* __restrict__ tb1,
                             const float* __restrict__ tw2,
                             const float* __restrict__ tb2,
                             float* __restrict__ tmean){
  __shared__ __align__(16) float s1[16*64];
  int j = threadIdx.x;
  float w1 = tw1[j], bb1 = tb1[j];
  for (int b = 0; b < 16; ++b)
    s1[b*64 + j] = siluf(t[b] * w1 + bb1);
  __syncthreads();
  float acc = 0.f;
  for (int b = 0; b < 16; ++b)
    for (int k = 0; k < 64; ++k)
      acc += s1[b*64 + k] * tw2[k*64 + j];
  tmean[j] = tb2[j] + acc * (1.f/16.f);
}

__global__ void init_h_kernel(const int* __restrict__ z,
                              const float* __restrict__ emb,
                              const float* __restrict__ tmean,
                              float* __restrict__ hf,
                              unsigned short* __restrict__ hb, int N){
  int i = blockIdx.x*256 + threadIdx.x;
  if (i >= N*64) return;
  int j = i & 63;
  int n = i >> 6;
  float v = emb[z[n]*64 + j] + tmean[j];
  hf[i] = v;
  hb[i] = f2b(v);
}

// ---------- p12: per-node MLP1 partials (layer 0 only; 1,2 fused into node) ----

__global__ __launch_bounds__(512) void p12_kernel(
    const unsigned short* __restrict__ hb,
    const float* __restrict__ ew1, const float* __restrict__ eb1,
    unsigned short* __restrict__ P1, unsigned short* __restrict__ P2,
    int layer, int N)
{
  __shared__ __align__(16) short w1a[64*72];
  __shared__ __align__(16) short w1b[64*72];
  __shared__ __align__(16) float b1s[64];

  const int tid = threadIdx.x;
  const float* w1g = ew1 + layer*129*64;
  for (int idx = tid; idx < 64*64; idx += 512){
    int k = idx >> 6, n = idx & 63;
    w1a[n*72 + k] = (short)f2b(w1g[k*64 + n]);
    w1b[n*72 + k] = (short)f2b(w1g[(64 + k)*64 + n]);
  }
  if (tid < 64) b1s[tid] = eb1[layer*64 + tid];
  __syncthreads();

  const int lane = tid & 63;
  const int wv = tid >> 6;
  const int q = lane >> 4;
  const int n16 = lane & 15;

  const int ntile = N >> 4;
  const int step = gridDim.x * 8;
  for (int t = blockIdx.x*8 + wv; t < ntile; t += step){
    const int row = t*16 + n16;
    const s8v* ph = (const s8v*)(hb + row*64);
    const s8v a0 = ph[q];
    const s8v a1 = ph[4+q];
    #pragma unroll
    for (int nt = 0; nt < 4; ++nt){
      const s8v* wa = (const s8v*)&w1a[(nt*16 + n16)*72];
      const s8v* wb = (const s8v*)&w1b[(nt*16 + n16)*72];
      f32x4 aA = {0.f,0.f,0.f,0.f};
      aA = MFMA16(a0, wa[q],   aA);
      aA = MFMA16(a1, wa[4+q], aA);
      f32x4 aB = {0.f,0.f,0.f,0.f};
      aB = MFMA16(a0, wb[q],   aB);
      aB = MFMA16(a1, wb[4+q], aB);
      const float bb = b1s[nt*16 + n16];
      #pragma unroll
      for (int r = 0; r < 4; ++r){
        const int o = (t*16 + q*4 + r)*64 + nt*16 + n16;
        P1[o] = f2b(aA[r] + bb);
        P2[o] = f2b(aB[r]);
      }
    }
  }
}

// ---------- edge kernel (CSR): one wave per dst node, NO atomics ----------
// (byte-identical to the proven 231 µs / VGPR 64 version — do not touch)

__global__ __launch_bounds__(512) void edge_csr_kernel(
    const int* __restrict__ rp, const int* __restrict__ csr_src,
    const float* __restrict__ x_in, float* __restrict__ x_out,
    const unsigned short* __restrict__ P1, const unsigned short* __restrict__ P2,
    unsigned short* __restrict__ aggb,
    const float* __restrict__ ew1,
    const float* __restrict__ ew2, const float* __restrict__ eb2,
    const float* __restrict__ cw1, const float* __restrict__ cb1,
    const float* __restrict__ cw2, const float* __restrict__ cb2,
    int layer, int do_agg, int N)
{
  __shared__ __align__(16) short wT2[64*72];    // e_w2^T [n][k]
  __shared__ __align__(16) short wc1T[64*72];   // c_w1^T
  __shared__ __align__(16) short sc[8][16*72];  // per-wave C->A transpose scratch
  __shared__ __align__(16) float sdiff[8][48];

  const int tid = threadIdx.x;
  const float* w2g = ew2 + layer*64*64;
  const float* c1g = cw1 + layer*64*64;
  for (int idx = tid; idx < 64*64; idx += 512){
    int k = idx >> 6, n = idx & 63;
    wT2[n*72 + k]  = (short)f2b(w2g[k*64 + n]);
    wc1T[n*72 + k] = (short)f2b(c1g[k*64 + n]);
  }

  const int lane = tid & 63;
  const int wv = tid >> 6;       // 0..7
  const int q = lane >> 4;       // quad 0..3
  const int n16 = lane & 15;
  short* mysc = sc[wv];
  float* mydiff = sdiff[wv];

  // per-lane loop-invariant constants in registers
  const float* wlg = ew1 + layer*129*64 + 128*64;
  float wl_lo[8], wl_hi[8];
  #pragma unroll
  for (int j = 0; j < 8; ++j){
    wl_lo[j] = wlg[q*8 + j];
    wl_hi[j] = wlg[32 + q*8 + j];
  }
  float be2r[4], bc1r[4], cw2r[4];
  #pragma unroll
  for (int nt = 0; nt < 4; ++nt){
    be2r[nt] = eb2[layer*64 + nt*16 + n16];
    bc1r[nt] = cb1[layer*64 + nt*16 + n16];
    cw2r[nt] = cw2[layer*64 + nt*16 + n16];
  }
  const float cb2s = cb2[layer];
  __syncthreads();

  const int nwave = gridDim.x * 8;
  for (int n = blockIdx.x*8 + wv; n < N; n += nwave){
    const int start = rp[n];
    const int deg = rp[n+1] - start;

    const s8v* pd = (const s8v*)(P1 + (size_t)n*64);
    const s8v lo1 = pd[q];
    const s8v hi1 = pd[4+q];
    const float xd0 = x_in[n*3+0];
    const float xd1 = x_in[n*3+1];
    const float xd2 = x_in[n*3+2];

    float colsum[4] = {0.f,0.f,0.f,0.f};
    float xacc0 = 0.f, xacc1 = 0.f, xacc2 = 0.f;

    const int nch = (deg + 15) >> 4;
    for (int c = 0; c < nch; ++c){
      const int row = c*16 + n16;
      const int si = (row < deg) ? csr_src[start + row] : n;  // pad: self -> diff=0
      const float xs0 = x_in[si*3+0];
      const float xs1 = x_in[si*3+1];
      const float xs2 = x_in[si*3+2];
      const float dx = xd0 - xs0;
      const float dy = xd1 - xs1;
      const float dz = xd2 - xs2;
      const float d2 = dx*dx + dy*dy + dz*dz;
      if (q == 0){ mydiff[n16*3+0]=dx; mydiff[n16*3+1]=dy; mydiff[n16*3+2]=dz; }

      const s8v* ps = (const s8v*)(P2 + (size_t)si*64);
      const s8v lo2 = ps[q];
      const s8v hi2 = ps[4+q];

      // MLP1 combine in registers (A-layout)
      s8v alo, ahi;
      #pragma unroll
      for (int j = 0; j < 8; ++j){
        const float v0 = b2f((unsigned short)lo1[j]) + b2f((unsigned short)lo2[j]) + d2*wl_lo[j];
        alo[j] = (short)f2b(siluf(v0));
        const float v1 = b2f((unsigned short)hi1[j]) + b2f((unsigned short)hi2[j]) + d2*wl_hi[j];
        ahi[j] = (short)f2b(siluf(v1));
      }

      // MLP2: (16x64)@(64x64)
      f32x4 acc2[4];
      #pragma unroll
      for (int nt = 0; nt < 4; ++nt){
        const s8v* wb = (const s8v*)&wT2[(nt*16 + n16)*72];
        f32x4 a = {0.f,0.f,0.f,0.f};
        a = MFMA16(alo, wb[q],   a);
        a = MFMA16(ahi, wb[4+q], a);
        acc2[nt] = a;
      }
      const int rowbase = c*16 + q*4;
      #pragma unroll
      for (int nt = 0; nt < 4; ++nt){
        const float bb = be2r[nt];
        #pragma unroll
        for (int r = 0; r < 4; ++r){
          const float mv = siluf(acc2[nt][r] + bb);
          mysc[(q*4 + r)*72 + nt*16 + n16] = (short)f2b(mv);
          colsum[nt] += (rowbase + r < deg) ? mv : 0.f;
        }
      }
      __builtin_amdgcn_wave_barrier();
      const s8v* srd = (const s8v*)&mysc[n16*72];
      const s8v m0 = srd[q];
      const s8v m1 = srd[4+q];
      __builtin_amdgcn_wave_barrier();

      // coord MLP: silu(m@c_w1+b) @ c_w2 + b
      float pr[4] = {0.f,0.f,0.f,0.f};
      #pragma unroll
      for (int nt = 0; nt < 4; ++nt){
        const s8v* wb = (const s8v*)&wc1T[(nt*16 + n16)*72];
        f32x4 a = {0.f,0.f,0.f,0.f};
        a = MFMA16(m0, wb[q],   a);
        a = MFMA16(m1, wb[4+q], a);
        const float bc = bc1r[nt];
        const float wc2 = cw2r[nt];
        #pragma unroll
        for (int r = 0; r < 4; ++r) pr[r] += siluf(a[r] + bc) * wc2;
      }
      #pragma unroll
      for (int off = 1; off < 16; off <<= 1){
        #pragma unroll
        for (int r = 0; r < 4; ++r) pr[r] += __shfl_xor(pr[r], off, 64);
      }
      #pragma unroll
      for (int r = 0; r < 4; ++r){
        const float cwv = pr[r] + cb2s;
        xacc0 += mydiff[(q*4 + r)*3 + 0] * cwv;
        xacc1 += mydiff[(q*4 + r)*3 + 1] * cwv;
        xacc2 += mydiff[(q*4 + r)*3 + 2] * cwv;
      }
    }

    #pragma unroll
    for (int nt = 0; nt < 4; ++nt){
      colsum[nt] += __shfl_xor(colsum[nt], 16, 64);
      colsum[nt] += __shfl_xor(colsum[nt], 32, 64);
    }
    xacc0 += __shfl_xor(xacc0, 16, 64); xacc0 += __shfl_xor(xacc0, 32, 64);
    xacc1 += __shfl_xor(xacc1, 16, 64); xacc1 += __shfl_xor(xacc1, 32, 64);
    xacc2 += __shfl_xor(xacc2, 16, 64); xacc2 += __shfl_xor(xacc2, 32, 64);

    if (do_agg && q == 0){
      #pragma unroll
      for (int nt = 0; nt < 4; ++nt)
        aggb[(size_t)n*64 + nt*16 + n16] = f2b(colsum[nt]);
    }
    if (lane == 0){
      x_out[n*3+0] = xd0 + xacc0;
      x_out[n*3+1] = xd1 + xacc1;
      x_out[n*3+2] = xd2 + xacc2;
    }
  }
}

// ---------- fused node + p12(next layer) ----------
// h' = h + MLP([h|agg]); then P1/P2 for layer+1 from h' (already in registers,
// via the same LDS transpose scratch) — saves a full h re-read + 2 dispatches.

__global__ __launch_bounds__(512) void node_p12_kernel(
    unsigned short* __restrict__ hb, float* __restrict__ hf,
    const unsigned short* __restrict__ aggb,
    const float* __restrict__ nw1, const float* __restrict__ nb1,
    const float* __restrict__ nw2, const float* __restrict__ nb2,
    const float* __restrict__ ew1, const float* __restrict__ eb1,
    unsigned short* __restrict__ P1, unsigned short* __restrict__ P2,
    int layer, int N)   // node layer = layer; p12 weights = layer+1
{
  __shared__ __align__(16) short wT1[64*136];
  __shared__ __align__(16) short wT2[64*72];
  __shared__ __align__(16) short w1a[64*72];
  __shared__ __align__(16) short w1b[64*72];
  __shared__ __align__(16) short sc[8][16*72];
  __shared__ __align__(16) float b1s[64];
  __shared__ __align__(16) float b2s[64];
  __shared__ __align__(16) float eb1s[64];

  const int tid = threadIdx.x;
  const float* w1g = nw1 + layer*128*64;
  const float* w2g = nw2 + layer*64*64;
  const float* e1g = ew1 + (layer+1)*129*64;
  for (int idx = tid; idx < 64*128; idx += 512){
    int k = idx >> 6, n = idx & 63;
    wT1[n*136 + k] = (short)f2b(w1g[k*64 + n]);
  }
  for (int idx = tid; idx < 64*64; idx += 512){
    int k = idx >> 6, n = idx & 63;
    wT2[n*72 + k] = (short)f2b(w2g[k*64 + n]);
    w1a[n*72 + k] = (short)f2b(e1g[k*64 + n]);
    w1b[n*72 + k] = (short)f2b(e1g[(64 + k)*64 + n]);
  }
  if (tid < 64){
    b1s[tid]  = nb1[layer*64 + tid];
    b2s[tid]  = nb2[layer*64 + tid];
    eb1s[tid] = eb1[(layer+1)*64 + tid];
  }
  __syncthreads();

  const int lane = tid & 63;
  const int wv = tid >> 6;
  const int q = lane >> 4;
  const int n16 = lane & 15;
  short* mysc = sc[wv];

  const int ntile = N >> 4;
  const int step = gridDim.x * 8;
  for (int t = blockIdx.x*8 + wv; t < ntile; t += step){
    const int row = t*16 + n16;
    const s8v* ph = (const s8v*)(hb + row*64);
    const s8v a0 = ph[q];
    const s8v a1 = ph[4+q];
    const s8v* pa = (const s8v*)(aggb + (size_t)row*64);
    const s8v a2 = pa[q];
    const s8v a3 = pa[4+q];

    // phase 1: g = silu([h|agg] @ n_w1 + b1) -> LDS (C->A transpose)
    #pragma unroll
    for (int nt = 0; nt < 4; ++nt){
      const s8v* wb = (const s8v*)&wT1[(nt*16 + n16)*136];
      f32x4 a = {0.f,0.f,0.f,0.f};
      a = MFMA16(a0, wb[q],    a);
      a = MFMA16(a1, wb[4+q],  a);
      a = MFMA16(a2, wb[8+q],  a);
      a = MFMA16(a3, wb[12+q], a);
      const float bb = b1s[nt*16 + n16];
      #pragma unroll
      for (int r = 0; r < 4; ++r)
        mysc[(q*4 + r)*72 + nt*16 + n16] = (short)f2b(siluf(a[r] + bb));
    }
    __builtin_amdgcn_wave_barrier();
    const s8v* srd = (const s8v*)&mysc[n16*72];
    const s8v g0 = srd[q];
    const s8v g1 = srd[4+q];
    __builtin_amdgcn_wave_barrier();

    // phase 2: h' = h + g @ n_w2 + b2 ; store hf/hb and stash bf16 h' to LDS
    #pragma unroll
    for (int nt = 0; nt < 4; ++nt){
      const s8v* wb = (const s8v*)&wT2[(nt*16 + n16)*72];
      f32x4 a = {0.f,0.f,0.f,0.f};
      a = MFMA16(g0, wb[q],   a);
      a = MFMA16(g1, wb[4+q], a);
      const float bb = b2s[nt*16 + n16];
      #pragma unroll
      for (int r = 0; r < 4; ++r){
        const int idx = (t*16 + q*4 + r)*64 + nt*16 + n16;
        const float hv = hf[idx] + a[r] + bb;
        hf[idx] = hv;
        const unsigned short hvb = f2b(hv);
        hb[idx] = hvb;
        mysc[(q*4 + r)*72 + nt*16 + n16] = (short)hvb;
      }
    }
    __builtin_amdgcn_wave_barrier();
    const s8v h0 = srd[q];
    const s8v h1 = srd[4+q];
    __builtin_amdgcn_wave_barrier();

    // phase 3: P1/P2 for layer+1 from h' (A-layout)
    #pragma unroll
    for (int nt = 0; nt < 4; ++nt){
      const s8v* wa = (const s8v*)&w1a[(nt*16 + n16)*72];
      const s8v* wb = (const s8v*)&w1b[(nt*16 + n16)*72];
      f32x4 aA = {0.f,0.f,0.f,0.f};
      aA = MFMA16(h0, wa[q],   aA);
      aA = MFMA16(h1, wa[4+q], aA);
      f32x4 aB = {0.f,0.f,0.f,0.f};
      aB = MFMA16(h0, wb[q],   aB);
      aB = MFMA16(h1, wb[4+q], aB);
      const float bb = eb1s[nt*16 + n16];
      #pragma unroll
      for (int r = 0; r < 4; ++r){
        const int o = (t*16 + q*4 + r)*64 + nt*16 + n16;
        P1[o] = f2b(aA[r] + bb);
        P2[o] = f2b(aB[r]);
      }
    }
  }
}

// ---------- launch ----------

extern "C" void kernel_launch(void* const* d_in, const int* in_sizes, int n_in,
                              void* d_out, int out_size, void* d_ws, size_t ws_size,
                              hipStream_t stream)
{
  // Inputs are fp32 (established R4..R12). Read d_in directly.
  const float* x0   = (const float*)d_in[0];
  const int*   z    = (const int*)d_in[1];
  const float* tc   = (const float*)d_in[2];
  const int*   ei   = (const int*)d_in[3];
  const float* embc = (const float*)d_in[4];
  const float* tw1c = (const float*)d_in[5];
  const float* tb1c = (const float*)d_in[6];
  const float* tw2c = (const float*)d_in[7];
  const float* tb2c = (const float*)d_in[8];
  const float* ew1c = (const float*)d_in[9];
  const float* eb1c = (const float*)d_in[10];
  const float* ew2c = (const float*)d_in[11];
  const float* eb2c = (const float*)d_in[12];
  const float* cw1c = (const float*)d_in[13];
  const float* cb1c = (const float*)d_in[14];
  const float* cw2c = (const float*)d_in[15];
  const float* cb2c = (const float*)d_in[16];
  const float* nw1c = (const float*)d_in[17];
  const float* nb1c = (const float*)d_in[18];
  const float* nw2c = (const float*)d_in[19];
  const float* nb2c = (const float*)d_in[20];

  const int N = in_sizes[1];
  const int E = in_sizes[3] / 2;
  const int* srcp = ei;
  const int* dstp = ei + E;

  char* p = (char*)d_ws;
  auto alloc = [&](size_t bytes) -> void* {
    void* r = (void*)p; p += (bytes + 255) & ~(size_t)255; return r;
  };
  float* hf            = (float*)alloc((size_t)N*64*4);
  unsigned short* hbuf = (unsigned short*)alloc((size_t)N*64*2);
  unsigned short* aggb = (unsigned short*)alloc((size_t)N*64*2);
  unsigned short* P1   = (unsigned short*)alloc((size_t)N*64*2);
  unsigned short* P2   = (unsigned short*)alloc((size_t)N*64*2);
  float* xa            = (float*)alloc((size_t)N*3*4);
  float* xb            = (float*)alloc((size_t)N*3*4);
  float* tmean         = (float*)alloc(64*4);
  int*   degcur        = (int*)alloc((size_t)2*N*4);   // deg | cursor (one memset)
  int*   deg           = degcur;
  int*   cursor        = degcur + N;
  int*   rowp          = (int*)alloc((size_t)(N+1)*4);
  int*   bsum          = (int*)alloc(256*4);
  int*   csr_src       = (int*)alloc((size_t)E*4);

  tmean_kernel<<<1, 64, 0, stream>>>(tc, tw1c, tb1c, tw2c, tb2c, tmean);
  init_h_kernel<<<(N*64 + 255)/256, 256, 0, stream>>>(z, embc, tmean, hf, hbuf, N);

  // ---- CSR build (once; edges fixed across layers) ----
  (void)hipMemsetAsync(degcur, 0, (size_t)2*N*4, stream);
  hist_kernel<<<(E + 255)/256, 256, 0, stream>>>(dstp, deg, E);
  const int nb = (N + 1023)/1024;
  scan1_kernel<<<nb, 256, 0, stream>>>(deg, rowp, bsum, N);
  scan2_kernel<<<1, 256, 0, stream>>>(bsum, nb);
  scan3_kernel<<<(N + 255)/256, 256, 0, stream>>>(rowp, bsum, N, E);
  scatter_kernel<<<(E + 255)/256, 256, 0, stream>>>(srcp, dstp, rowp, cursor, csr_src, E);

  // layer-0 partials standalone; layers 1,2 fused into node_p12
  p12_kernel<<<512, 512, 0, stream>>>(hbuf, ew1c, eb1c, P1, P2, 0, N);

  const float* xc = x0;
  float* xnexts[3] = {xa, xb, (float*)d_out};
  for (int l = 0; l < 3; ++l){
    float* xout = xnexts[l];
    edge_csr_kernel<<<1024, 512, 0, stream>>>(rowp, csr_src, xc, xout, P1, P2, aggb,
        ew1c, ew2c, eb2c, cw1c, cb1c, cw2c, cb2c, l, (l < 2) ? 1 : 0, N);
    if (l < 2)
      node_p12_kernel<<<512, 512, 0, stream>>>(hbuf, hf, aggb,
          nw1c, nb1c, nw2c, nb2c, ew1c, eb1c, P1, P2, l, N);
    xc = xout;
  }
}